// Round 6
// baseline (282.677 us; speedup 1.0000x reference)
//
#include <hip/hip_runtime.h>
#include <hip/hip_bf16.h>
#include <math.h>

typedef __bf16 bf16x8 __attribute__((ext_vector_type(8)));
typedef float f32x4 __attribute__((ext_vector_type(4)));

#define GAS __attribute__((address_space(1)))
#define LAS __attribute__((address_space(3)))

static __device__ __forceinline__ void load16(const void* g, void* l) {
    __builtin_amdgcn_global_load_lds((const GAS void*)g, (LAS void*)l, 16, 0, 0);
}

struct __align__(8) bh4 { __hip_bfloat16 x, y, z, w; };

// ---------- fused LayerNorm (blocks 0..nln-1) + weight cast (blocks nln..) ----------
__global__ __launch_bounds__(256) void pre_kernel(
        const float* __restrict__ x, const float* __restrict__ gamma,
        const float* __restrict__ beta, const float* __restrict__ w1,
        const float* __restrict__ w2, __hip_bfloat16* __restrict__ hn,
        __hip_bfloat16* __restrict__ w1b, __hip_bfloat16* __restrict__ w2b, int nln) {
    if ((int)blockIdx.x >= nln) {   // weight cast: 1024 blocks x 256 thr x 4 elems
        const int i = (blockIdx.x - nln) * 256 + threadIdx.x;
        float4 a = ((const float4*)w1)[i];
        float4 b = ((const float4*)w2)[i];
        bh4 r1, r2;
        r1.x = __float2bfloat16(a.x); r1.y = __float2bfloat16(a.y);
        r1.z = __float2bfloat16(a.z); r1.w = __float2bfloat16(a.w);
        r2.x = __float2bfloat16(b.x); r2.y = __float2bfloat16(b.y);
        r2.z = __float2bfloat16(b.z); r2.w = __float2bfloat16(b.w);
        ((bh4*)w1b)[i] = r1;
        ((bh4*)w2b)[i] = r2;
        return;
    }
    const int row  = (blockIdx.x << 2) + (threadIdx.x >> 6);
    const int lane = threadIdx.x & 63;
    const float4* px = (const float4*)(x + (size_t)row * 1024);
    float4 v[4];
    float s = 0.f;
#pragma unroll
    for (int i = 0; i < 4; ++i) {
        v[i] = px[lane + (i << 6)];
        s += v[i].x + v[i].y + v[i].z + v[i].w;
    }
#pragma unroll
    for (int o = 32; o; o >>= 1) s += __shfl_xor(s, o, 64);
    const float mu = s * (1.0f / 1024.0f);
    float vs = 0.f;
#pragma unroll
    for (int i = 0; i < 4; ++i) {
        float a = v[i].x - mu, b = v[i].y - mu, c = v[i].z - mu, d = v[i].w - mu;
        vs += a * a + b * b + c * c + d * d;
    }
#pragma unroll
    for (int o = 32; o; o >>= 1) vs += __shfl_xor(vs, o, 64);
    const float rs = rsqrtf(vs * (1.0f / 1024.0f) + 1e-5f);
    const float4* pg = (const float4*)gamma;
    const float4* pb = (const float4*)beta;
    bh4* po = (bh4*)(hn + (size_t)row * 1024);
#pragma unroll
    for (int i = 0; i < 4; ++i) {
        const int idx = lane + (i << 6);
        float4 g = pg[idx], bb = pb[idx];
        bh4 r;
        r.x = __float2bfloat16((v[i].x - mu) * rs * g.x + bb.x);
        r.y = __float2bfloat16((v[i].y - mu) * rs * g.y + bb.y);
        r.z = __float2bfloat16((v[i].z - mu) * rs * g.z + bb.z);
        r.w = __float2bfloat16((v[i].w - mu) * rs * g.w + bb.w);
        po[idx] = r;
    }
}

// ---------- GEMM (B^T weights), 128x256 tile, BK=64, 2-barrier loop, MFMA 16x16x32 ----
// Grid = 128 x 4 = 512 blocks = exactly 2/CU -> ONE uniform generation, no tail.
// 4 waves, each computes 64x128 (acc[4][8]); 64 MFMA per barrier-pair per wave.
// NO cross-barrier prefetch (round 5's race); plain proven structure:
//   stage tile kt (12x load16) -> barrier -> 24x ds_read_b128 + 64 MFMA -> barrier.
// LDS 48 KB single-buffered:
//   sA @0     128 rows x 128 B, chunk XOR key (row&7)    (round-3 verified layout)
//   sB @16384 256 rows x 128 B, chunk XOR key ((row>>2)&7)
// Fragment reads hit 8 accesses/bank = minimum; staging contiguous 64-B segments;
// epilogue: lane owns 4 contiguous output columns per column-group.
// EPI==0: out_bf16 = gelu(A*B^T + bias); EPI==1: out_f32 = A*B^T + bias + resid
template <int EPI>
__global__ __launch_bounds__(256) void gemm_kernel(
        const __hip_bfloat16* __restrict__ A,
        const __hip_bfloat16* __restrict__ B,
        const float* __restrict__ bias,
        const float* __restrict__ resid,
        __hip_bfloat16* __restrict__ outb,
        float* __restrict__ outf) {
    constexpr int K = 1024, N = 1024;
    __shared__ __align__(16) char lds[49152];   // sA 16 KB + sB 32 KB

    const int tid  = threadIdx.x;
    const int lane = tid & 63;
    const int w    = tid >> 6;
    const int wm   = (w >> 1) * 64;    // wave row base in tile
    const int wn2  = (w & 1) * 128;    // wave col base in tile
    const int bm   = blockIdx.x * 128;
    const int bn   = blockIdx.y * 256;
    const int f = lane & 15;
    const int h = lane >> 4;

    // ---- staging sources (identity rows, chunk permuted per XOR key) ----
    const int srow = tid >> 3;                          // base row (+q*32)
    const int cA = (tid & 7) ^ (srow & 7);              // A key = row&7 (row+32q: same)
    const int cB = (tid & 7) ^ ((tid >> 5) & 7);        // B key = (row>>2)&7 (same for all q)
    const __hip_bfloat16* gA = A + (size_t)(bm + srow) * K + cA * 8;   // + q*32*K, q=0..3
    const __hip_bfloat16* gB = B + (size_t)(bn + srow) * K + cB * 8;   // + q*32*K, q=0..7
    char* dA = lds + tid * 16;            // + q*4096
    char* dB = lds + 16384 + tid * 16;    // + q*4096

    // ---- fragment read bases (loop-invariant) ----
    const int pxk = (f & 7) * 16;
    const int px0 = (h * 16) ^ pxk;             // c=0: chunk h ^ (f&7)
    const int px1 = ((4 + h) * 16) ^ pxk;       // c=1: chunk (4+h) ^ (f&7)
    const char* aBase = lds + (wm + f) * 128;                     // + i*2048 + px
    const char* bBase0 = lds + 16384 + (wn2 + 4 * f) * 128;       // g=0: + j*128 + px
    const char* bBase1 = bBase0 + 64 * 128;                       // g=1

    f32x4 acc[4][8] = {};

    for (int kt = 0; kt < K; kt += 64) {
#pragma unroll
        for (int q = 0; q < 4; ++q)
            load16(gA + kt + (size_t)(q * 32) * K, dA + q * 4096);
#pragma unroll
        for (int q = 0; q < 8; ++q)
            load16(gB + kt + (size_t)(q * 32) * K, dB + q * 4096);
        __syncthreads();                       // drain own vmcnt: tile visible
#pragma unroll
        for (int c = 0; c < 2; ++c) {
            const int px = c ? px1 : px0;
            bf16x8 af[4];
#pragma unroll
            for (int i = 0; i < 4; ++i)
                af[i] = *(const bf16x8*)(aBase + i * 2048 + px);
#pragma unroll
            for (int g = 0; g < 2; ++g) {
                const char* bb = g ? bBase1 : bBase0;
                bf16x8 bf[4];
#pragma unroll
                for (int j = 0; j < 4; ++j)
                    bf[j] = *(const bf16x8*)(bb + j * 128 + px);
#pragma unroll
                for (int i = 0; i < 4; ++i)
#pragma unroll
                    for (int j = 0; j < 4; ++j)
                        acc[i][g * 4 + j] =
                            __builtin_amdgcn_mfma_f32_16x16x32_bf16(af[i], bf[j], acc[i][g * 4 + j], 0, 0, 0);
            }
        }
        __syncthreads();                       // reads done before next overwrite
    }

    // epilogue: lane owns rows wm+i*16+h*4+r; cols bn+wn2+{0,64}+4f..+3
    const int colb0 = bn + wn2 + f * 4;
    const float4 bias4a = *(const float4*)(bias + colb0);
    const float4 bias4b = *(const float4*)(bias + colb0 + 64);
#pragma unroll
    for (int i = 0; i < 4; ++i) {
#pragma unroll
        for (int r = 0; r < 4; ++r) {
            const size_t grow = (size_t)(bm + wm + i * 16 + h * 4 + r);
#pragma unroll
            for (int g = 0; g < 2; ++g) {
                const float4 b4 = g ? bias4b : bias4a;
                const int col = colb0 + g * 64;
                float v0 = acc[i][g * 4 + 0][r] + b4.x;
                float v1 = acc[i][g * 4 + 1][r] + b4.y;
                float v2 = acc[i][g * 4 + 2][r] + b4.z;
                float v3 = acc[i][g * 4 + 3][r] + b4.w;
                if (EPI == 0) {
                    bh4 o;
                    o.x = __float2bfloat16(0.5f * v0 * (1.0f + erff(v0 * 0.70710678118654752f)));
                    o.y = __float2bfloat16(0.5f * v1 * (1.0f + erff(v1 * 0.70710678118654752f)));
                    o.z = __float2bfloat16(0.5f * v2 * (1.0f + erff(v2 * 0.70710678118654752f)));
                    o.w = __float2bfloat16(0.5f * v3 * (1.0f + erff(v3 * 0.70710678118654752f)));
                    *(bh4*)(outb + grow * N + col) = o;
                } else {
                    const float4 rs = *(const float4*)(resid + grow * N + col);
                    float4 o = {v0 + rs.x, v1 + rs.y, v2 + rs.z, v3 + rs.w};
                    *(float4*)(outf + grow * N + col) = o;
                }
            }
        }
    }
}

extern "C" void kernel_launch(void* const* d_in, const int* in_sizes, int n_in,
                              void* d_out, int out_size, void* d_ws, size_t ws_size,
                              hipStream_t stream) {
    const float* x     = (const float*)d_in[0];
    const float* gamma = (const float*)d_in[1];
    const float* beta  = (const float*)d_in[2];
    const float* w1    = (const float*)d_in[3];
    const float* b1    = (const float*)d_in[4];
    const float* w2    = (const float*)d_in[5];
    const float* b2    = (const float*)d_in[6];
    float* out = (float*)d_out;

    const int M = in_sizes[0] / 1024;   // 16384

    char* ws = (char*)d_ws;
    __hip_bfloat16* hn  = (__hip_bfloat16*)ws;                          // 32 MiB
    __hip_bfloat16* h1  = (__hip_bfloat16*)(ws + (size_t)M * 2048);     // 32 MiB
    __hip_bfloat16* w1b = (__hip_bfloat16*)(ws + (size_t)M * 4096);     // 2 MiB
    __hip_bfloat16* w2b = (__hip_bfloat16*)(ws + (size_t)M * 4096 + 2097152);

    const int nln = M / 4;   // 4096 LN blocks + 1024 cvt blocks
    pre_kernel<<<nln + 1024, 256, 0, stream>>>(x, gamma, beta, w1, w2, hn, w1b, w2b, nln);
    // 512 blocks = 2/CU exactly; same-bm blocks (ids 128 apart == 0 mod 8) share an XCD
    gemm_kernel<0><<<dim3(M / 128, 4), 256, 0, stream>>>(hn, w1b, b1, nullptr, h1, nullptr);
    gemm_kernel<1><<<dim3(M / 128, 4), 256, 0, stream>>>(h1, w2b, b2, x, nullptr, out);
}